// Round 1
// baseline (1841.050 us; speedup 1.0000x reference)
//
#include <hip/hip_runtime.h>
#include <hip/hip_fp16.h>

typedef _Float16 f16;
typedef _Float16 half8 __attribute__((ext_vector_type(8)));
typedef float floatx4 __attribute__((ext_vector_type(4)));

constexpr int kH  = 2048;
constexpr int kS  = 2048;
constexpr int kB  = 2;
constexpr int kT  = kB * kS;   // 4096 tokens
constexpr int kNH = 16;
constexpr int kHD = 128;
constexpr int kE  = 8;
constexpr int kF  = 8192;
constexpr int kCAP = 1280;     // ceil(T*K/E*1.25)
constexpr int kTK = kT * 2;

__device__ __forceinline__ void gload16(const void* g, void* lds) {
  __builtin_amdgcn_global_load_lds((const __attribute__((address_space(1))) void*)g,
                                   (__attribute__((address_space(3))) void*)lds,
                                   16, 0, 0);
}

// ---------------- transpose + fp32->fp16 convert: src[K][N] -> dst[N][K] ----
__global__ __launch_bounds__(256) void transpose_cvt(
    const float* __restrict__ src, f16* __restrict__ dst,
    int ldS, int ldD, long sZ, long dZ)
{
  __shared__ float tile[64][65];
  src += (long)blockIdx.z * sZ;
  dst += (long)blockIdx.z * dZ;
  const int kb = blockIdx.y * 64, nb = blockIdx.x * 64;
  const int tx = threadIdx.x & 15, ty = threadIdx.x >> 4;
#pragma unroll
  for (int i = 0; i < 4; i++) {
    const int r = ty + i * 16;
    const float4 v = *(const float4*)&src[(long)(kb + r) * ldS + nb + tx * 4];
    tile[r][tx * 4 + 0] = v.x; tile[r][tx * 4 + 1] = v.y;
    tile[r][tx * 4 + 2] = v.z; tile[r][tx * 4 + 3] = v.w;
  }
  __syncthreads();
#pragma unroll
  for (int i = 0; i < 4; i++) {
    const int n = ty + i * 16;
    union { f16 h[4]; unsigned long long u; } pk;
#pragma unroll
    for (int j = 0; j < 4; j++) pk.h[j] = (f16)tile[tx * 4 + j][n];
    *(unsigned long long*)&dst[(long)(nb + n) * ldD + kb + tx * 4] = pk.u;
  }
}

// ---------------- layernorm: one block (256 thr) per row of 2048 ------------
__global__ __launch_bounds__(256) void ln_kernel(
    const float* __restrict__ x, const float* __restrict__ sc,
    const float* __restrict__ bi, f16* __restrict__ o16, float* __restrict__ o32)
{
  const long row = blockIdx.x;
  const float* xr = x + row * kH;
  const int t = threadIdx.x;
  const float4 u = ((const float4*)xr)[t * 2];
  const float4 v = ((const float4*)xr)[t * 2 + 1];
  float s = u.x + u.y + u.z + u.w + v.x + v.y + v.z + v.w;
  float q = u.x*u.x + u.y*u.y + u.z*u.z + u.w*u.w + v.x*v.x + v.y*v.y + v.z*v.z + v.w*v.w;
#pragma unroll
  for (int m = 1; m < 64; m <<= 1) { s += __shfl_xor(s, m); q += __shfl_xor(q, m); }
  __shared__ float red_s[4], red_q[4];
  const int w = t >> 6, l = t & 63;
  if (l == 0) { red_s[w] = s; red_q[w] = q; }
  __syncthreads();
  s = red_s[0] + red_s[1] + red_s[2] + red_s[3];
  q = red_q[0] + red_q[1] + red_q[2] + red_q[3];
  const float mean = s * (1.f / kH);
  const float var = q * (1.f / kH) - mean * mean;
  const float rstd = rsqrtf(var + 1e-5f);
  const int c = t * 8;
  const float vals[8] = {u.x, u.y, u.z, u.w, v.x, v.y, v.z, v.w};
#pragma unroll
  for (int j = 0; j < 8; j++) {
    const float y = (vals[j] - mean) * rstd * sc[c + j] + bi[c + j];
    o16[row * kH + c + j] = (f16)y;
    if (o32 != nullptr) o32[row * kH + c + j] = y;
  }
}

// ---------------- GEMM: C[M][N] = A[M][K] * B^T[N][K], f16 in / f32 acc -----
// 128x128 tile, BK=64, 4 waves (2x2 of 64x64), swizzled LDS (XOR (row&7)<<4).
template <int EPI>  // 0: f32 store; 2: f16 gelu(x+bias); 3: f16 x+bias
__global__ __launch_bounds__(256) void gemm_kernel(
    const f16* __restrict__ A, const f16* __restrict__ B, void* __restrict__ Cv,
    const float* __restrict__ bias, const int* __restrict__ rowCount,
    int M, int N, int K, long aZ, long bZ, long cZ, long biasZ)
{
  const int z = blockIdx.z;
  if (rowCount != nullptr && (int)(blockIdx.y * 128) >= rowCount[z]) return;
  __shared__ f16 As[128 * 64];
  __shared__ f16 Bs[128 * 64];
  A += (long)z * aZ;  B += (long)z * bZ;
  const int tid = threadIdx.x, w = tid >> 6, l = tid & 63;
  const int g = l >> 4, lr = l & 15;
  const long m0 = (long)blockIdx.y * 128, n0 = (long)blockIdx.x * 128;
  const int wm = (w >> 1) * 64, wn = (w & 1) * 64;
  floatx4 acc[4][4];
#pragma unroll
  for (int i = 0; i < 4; i++)
#pragma unroll
    for (int j = 0; j < 4; j++) acc[i][j] = floatx4{0.f, 0.f, 0.f, 0.f};
  const int lrow = l >> 3, lwb = (l & 7) * 16;
  const int nk = K >> 6;
  for (int kt = 0; kt < nk; kt++) {
    const long k0 = (long)kt * 64;
#pragma unroll
    for (int c = 0; c < 4; c++) {
      const int rbase = w * 32 + c * 8;
      const int row = rbase + lrow;
      const int srcoff = (lwb ^ ((row & 7) << 4)) >> 1;
      gload16(A + (m0 + row) * K + k0 + srcoff, As + rbase * 64);
      gload16(B + (n0 + row) * K + k0 + srcoff, Bs + rbase * 64);
    }
    asm volatile("s_waitcnt vmcnt(0)" ::: "memory");
    __syncthreads();
#pragma unroll
    for (int kc = 0; kc < 2; kc++) {
      half8 af[4], bf[4];
#pragma unroll
      for (int i = 0; i < 4; i++) {
        const int ra = wm + i * 16 + lr;
        af[i] = *(const half8*)((const char*)As + ra * 128 + ((kc * 64 + g * 16) ^ ((ra & 7) << 4)));
        const int rb = wn + i * 16 + lr;
        bf[i] = *(const half8*)((const char*)Bs + rb * 128 + ((kc * 64 + g * 16) ^ ((rb & 7) << 4)));
      }
#pragma unroll
      for (int mi = 0; mi < 4; mi++)
#pragma unroll
        for (int ni = 0; ni < 4; ni++)
          acc[mi][ni] = __builtin_amdgcn_mfma_f32_16x16x32_f16(af[mi], bf[ni], acc[mi][ni], 0, 0, 0);
    }
    __syncthreads();
  }
  const long crow = m0 + wm + g * 4;
  const long ccol = n0 + wn + lr;
#pragma unroll
  for (int mi = 0; mi < 4; mi++)
#pragma unroll
    for (int ni = 0; ni < 4; ni++)
#pragma unroll
      for (int j = 0; j < 4; j++) {
        const long r = crow + mi * 16 + j;
        const long c = ccol + ni * 16;
        float v = acc[mi][ni][j];
        if (EPI == 0) {
          ((float*)Cv)[(long)z * cZ + r * N + c] = v;
        } else if (EPI == 2) {
          v += bias[(long)z * biasZ + c];
          const float t2 = tanhf(0.7978845608028654f * (v + 0.044715f * v * v * v));
          ((f16*)Cv)[(long)z * cZ + r * N + c] = (f16)(0.5f * v * (1.f + t2));
        } else {
          v += bias[(long)z * biasZ + c];
          ((f16*)Cv)[(long)z * cZ + r * N + c] = (f16)v;
        }
      }
}

// ---------------- RoPE table (double precision trig, fp32 out) --------------
__global__ void rope_table_kernel(float* __restrict__ ct, float* __restrict__ st) {
  const int i = blockIdx.x * 256 + threadIdx.x;
  if (i >= kS * 64) return;
  const int s = i >> 6, f = i & 63;
  const double freq = exp(-0.14391156831212787 * (double)f);  // ln(10000)/64
  const double ang = (double)s * freq;
  ct[i] = (float)cos(ang);
  st[i] = (float)sin(ang);
}

// ---------------- RoPE apply + relayout to [BH][S][HD], q scaled ------------
__global__ __launch_bounds__(256) void rope_kernel(
    const float* __restrict__ q, const float* __restrict__ k,
    const float* __restrict__ ct, const float* __restrict__ st,
    f16* __restrict__ qr, f16* __restrict__ kr)
{
  const long t = blockIdx.x;            // b*S + s
  const int s = (int)(t & (kS - 1)), b = (int)(t >> 11);
  for (int u = threadIdx.x; u < kNH * 64; u += 256) {
    const int h = u >> 6, i = u & 63;
    const float c = ct[s * 64 + i], sn = st[s * 64 + i];
    const long src = t * kH + h * kHD + i;
    const long dst = (((long)(b * kNH + h)) * kS + s) * kHD + i;
    float x1 = q[src], x2 = q[src + 64];
    qr[dst]      = (f16)((x1 * c - x2 * sn) * 0.08838834764831845f);
    qr[dst + 64] = (f16)((x1 * sn + x2 * c) * 0.08838834764831845f);
    x1 = k[src]; x2 = k[src + 64];
    kr[dst]      = (f16)(x1 * c - x2 * sn);
    kr[dst + 64] = (f16)(x1 * sn + x2 * c);
  }
}

// ---------------- causal flash attention ------------------------------------
// grid (S/64, NH, B); 4 waves, each owns 16 q-rows. K/V tiles of 64 in LDS.
__global__ __launch_bounds__(256) void attn_kernel(
    const f16* __restrict__ q_r, const f16* __restrict__ k_r,
    const f16* __restrict__ v_t, f16* __restrict__ ctx)
{
  __shared__ f16 Ks[64 * 128];    // [key][d], swizzled
  __shared__ f16 Vs[128 * 64];    // [d][kk], swizzled
  __shared__ f16 Ps[4][1024];     // per-wave P [16][64], swizzled
  const int qt = blockIdx.x, h = blockIdx.y, b = blockIdx.z;
  const int bh = b * kNH + h;
  const int tid = threadIdx.x, w = tid >> 6, l = tid & 63;
  const int g = l >> 4, lr = l & 15;
  const long q0 = (long)qt * 64;
  const f16* qbase = q_r + ((long)bh * kS + q0 + w * 16 + lr) * kHD;
  half8 qf[4];
#pragma unroll
  for (int kc = 0; kc < 4; kc++) qf[kc] = *(const half8*)(qbase + kc * 32 + g * 8);
  floatx4 acc[8];
#pragma unroll
  for (int i = 0; i < 8; i++) acc[i] = floatx4{0.f, 0.f, 0.f, 0.f};
  float mrun[4], lrun[4];
#pragma unroll
  for (int j = 0; j < 4; j++) { mrun[j] = -1e30f; lrun[j] = 0.f; }
  f16* pw = Ps[w];

  for (int kt = 0; kt <= qt; kt++) {
    const long k0 = (long)kt * 64;
#pragma unroll
    for (int c = 0; c < 4; c++) {              // K tile: 16 x 1KB
      const int cc = w * 4 + c;
      const int row = cc * 4 + (l >> 4);
      const int wb = (l & 15) * 16;
      const int src = (wb ^ ((row & 7) << 4)) >> 1;
      gload16(k_r + ((long)bh * kS + k0 + row) * kHD + src, Ks + cc * 512);
    }
#pragma unroll
    for (int c = 0; c < 4; c++) {              // V tile (transposed layout)
      const int cc = w * 4 + c;
      const int row = cc * 8 + (l >> 3);
      const int wb = (l & 7) * 16;
      const int src = (wb ^ ((row & 7) << 4)) >> 1;
      gload16(v_t + ((long)bh * kHD + row) * kS + k0 + src, Vs + cc * 512);
    }
    asm volatile("s_waitcnt vmcnt(0)" ::: "memory");
    __syncthreads();

    floatx4 sfr[4];
#pragma unroll
    for (int f = 0; f < 4; f++) {              // QK^T
      floatx4 s4 = floatx4{0.f, 0.f, 0.f, 0.f};
      const int row = f * 16 + lr;
#pragma unroll
      for (int kc = 0; kc < 4; kc++) {
        const half8 kfq = *(const half8*)((const char*)Ks + row * 256 +
                            ((kc * 64 + g * 16) ^ ((row & 7) << 4)));
        s4 = __builtin_amdgcn_mfma_f32_16x16x32_f16(qf[kc], kfq, s4, 0, 0, 0);
      }
      sfr[f] = s4;
    }
    if (kt == qt) {                            // diagonal causal mask
#pragma unroll
      for (int f = 0; f < 4; f++) {
        const int key = kt * 64 + f * 16 + lr;
#pragma unroll
        for (int j = 0; j < 4; j++) {
          const int qrow = qt * 64 + w * 16 + g * 4 + j;
          if (key > qrow) sfr[f][j] = -1e30f;
        }
      }
    }
    float al[4];
#pragma unroll
    for (int j = 0; j < 4; j++) {              // online softmax per row
      float pm = fmaxf(fmaxf(sfr[0][j], sfr[1][j]), fmaxf(sfr[2][j], sfr[3][j]));
      pm = fmaxf(pm, __shfl_xor(pm, 1)); pm = fmaxf(pm, __shfl_xor(pm, 2));
      pm = fmaxf(pm, __shfl_xor(pm, 4)); pm = fmaxf(pm, __shfl_xor(pm, 8));
      const float mn = fmaxf(mrun[j], pm);
      al[j] = __expf(mrun[j] - mn);
      mrun[j] = mn;
      float rs = 0.f;
#pragma unroll
      for (int f = 0; f < 4; f++) {
        const float p = __expf(sfr[f][j] - mn);
        sfr[f][j] = p; rs += p;
      }
      rs += __shfl_xor(rs, 1); rs += __shfl_xor(rs, 2);
      rs += __shfl_xor(rs, 4); rs += __shfl_xor(rs, 8);
      lrun[j] = lrun[j] * al[j] + rs;
    }
#pragma unroll
    for (int nf = 0; nf < 8; nf++)
#pragma unroll
      for (int j = 0; j < 4; j++) acc[nf][j] *= al[j];
#pragma unroll
    for (int f = 0; f < 4; f++)                // P -> per-wave LDS (swizzled)
#pragma unroll
      for (int j = 0; j < 4; j++) {
        const int row = g * 4 + j;
        const int byteoff = (row * 128 + (f * 16 + lr) * 2) ^ ((row & 7) << 4);
        *(f16*)((char*)pw + byteoff) = (f16)sfr[f][j];
      }
#pragma unroll
    for (int kc = 0; kc < 2; kc++) {           // PV
      const half8 pf = *(const half8*)((const char*)pw + lr * 128 +
                         ((kc * 64 + g * 16) ^ ((lr & 7) << 4)));
#pragma unroll
      for (int nf = 0; nf < 8; nf++) {
        const int vrow = nf * 16 + lr;
        const half8 vfr = *(const half8*)((const char*)Vs + vrow * 128 +
                            ((kc * 64 + g * 16) ^ ((vrow & 7) << 4)));
        acc[nf] = __builtin_amdgcn_mfma_f32_16x16x32_f16(pf, vfr, acc[nf], 0, 0, 0);
      }
    }
    __syncthreads();
  }
  const long orow = (long)b * kS + q0 + w * 16;
#pragma unroll
  for (int j = 0; j < 4; j++) {
    const float inv = 1.0f / lrun[j];
    const int r = g * 4 + j;
#pragma unroll
    for (int nf = 0; nf < 8; nf++)
      ctx[(orow + r) * kH + h * kHD + nf * 16 + lr] = (f16)(acc[nf][j] * inv);
  }
}

// ---------------- residual 1: h2 = hidden + ls*(attn_lin * sigmoid(g+bg)) ---
__global__ __launch_bounds__(256) void combine1_kernel(
    const float* __restrict__ hid, const float* __restrict__ alin,
    const float* __restrict__ glin, const float* __restrict__ bg,
    const float* __restrict__ ls, float* __restrict__ out)
{
  const long i = (long)blockIdx.x * 256 + threadIdx.x;
  const float4 hv = ((const float4*)hid)[i];
  const float4 av = ((const float4*)alin)[i];
  const float4 gv = ((const float4*)glin)[i];
  const int c = (int)(i & 511);
  const float4 lv = ((const float4*)ls)[c];
  const float4 bv = ((const float4*)bg)[c];
  float4 o;
  o.x = hv.x + lv.x * av.x / (1.f + __expf(-(gv.x + bv.x)));
  o.y = hv.y + lv.y * av.y / (1.f + __expf(-(gv.y + bv.y)));
  o.z = hv.z + lv.z * av.z / (1.f + __expf(-(gv.z + bv.z)));
  o.w = hv.w + lv.w * av.w / (1.f + __expf(-(gv.w + bv.w)));
  ((float4*)out)[i] = o;
}

// ---------------- router: logits(fp32) -> softmax -> top2 -> gates ----------
__global__ __launch_bounds__(256) void router_kernel(
    const float* __restrict__ x, const float* __restrict__ rw,
    int* __restrict__ eidx, float* __restrict__ gates)
{
  const int t = blockIdx.x * 4 + (threadIdx.x >> 6);
  const int l = threadIdx.x & 63;
  const float* xr = x + (long)t * kH;
  float a[8] = {0.f, 0.f, 0.f, 0.f, 0.f, 0.f, 0.f, 0.f};
  for (int it = 0; it < kH / 64; it++) {
    const float xv = xr[it * 64 + l];
    const float* r = rw + (long)(it * 64 + l) * kE;
#pragma unroll
    for (int e = 0; e < 8; e++) a[e] += xv * r[e];
  }
#pragma unroll
  for (int e = 0; e < 8; e++)
#pragma unroll
    for (int m = 1; m < 64; m <<= 1) a[e] += __shfl_xor(a[e], m);
  if (l == 0) {
    float mx = a[0];
#pragma unroll
    for (int e = 1; e < 8; e++) mx = fmaxf(mx, a[e]);
    float p[8];
#pragma unroll
    for (int e = 0; e < 8; e++) p[e] = __expf(a[e] - mx);
    int i1 = 0; float v1 = p[0];
#pragma unroll
    for (int e = 1; e < 8; e++) if (p[e] > v1) { v1 = p[e]; i1 = e; }
    int i2 = -1; float v2 = -1.f;
#pragma unroll
    for (int e = 0; e < 8; e++) if (e != i1 && p[e] > v2) { v2 = p[e]; i2 = e; }
    const float inv = 1.f / (v1 + v2);
    eidx[t * 2] = i1; eidx[t * 2 + 1] = i2;
    gates[t * 2] = v1 * inv; gates[t * 2 + 1] = v2 * inv;
  }
}

// ---------------- deterministic capacity scan (single wave) -----------------
__global__ void scan_kernel(const int* __restrict__ eidx, int* __restrict__ slot,
                            int* __restrict__ counts)
{
  const int l = threadIdx.x;
  int base[8] = {0, 0, 0, 0, 0, 0, 0, 0};
  const unsigned long long lt = (1ull << l) - 1ull;
  for (int it = 0; it < kTK / 64; it++) {
    const int i = it * 64 + l;
    const int e = eidx[i];
    int mypos = 0;
#pragma unroll
    for (int ex = 0; ex < 8; ex++) {
      const unsigned long long mk = __ballot(e == ex);
      if (e == ex) mypos = base[ex] + __popcll(mk & lt);
      base[ex] += __popcll(mk);
    }
    slot[i] = (mypos < kCAP) ? e * kCAP + mypos : -1;
  }
  if (l == 0) {
#pragma unroll
    for (int ex = 0; ex < 8; ex++) counts[ex] = min(base[ex], kCAP);
  }
}

// ---------------- scatter tokens into expert buffers ------------------------
__global__ __launch_bounds__(256) void scatter_kernel(
    const f16* __restrict__ xh, const int* __restrict__ slot, f16* __restrict__ buf)
{
  const int i = blockIdx.x;
  const int s = slot[i];
  if (s < 0) return;
  const long t = i >> 1;
  ((half8*)(buf + (long)s * kH))[threadIdx.x] =
      ((const half8*)(xh + t * kH))[threadIdx.x];
}

// ---------------- final combine ---------------------------------------------
__global__ __launch_bounds__(256) void combine2_kernel(
    const float* __restrict__ hid2, const f16* __restrict__ obuf,
    const int* __restrict__ slot, const float* __restrict__ gates,
    const float* __restrict__ ls, float* __restrict__ out)
{
  const int t = blockIdx.x;
  const int s0 = slot[t * 2], s1 = slot[t * 2 + 1];
  const float g0 = (s0 >= 0) ? gates[t * 2] : 0.f;
  const float g1 = (s1 >= 0) ? gates[t * 2 + 1] : 0.f;
  const f16* o0 = obuf + (long)(s0 < 0 ? 0 : s0) * kH;
  const f16* o1 = obuf + (long)(s1 < 0 ? 0 : s1) * kH;
  const int c = threadIdx.x * 8;
  const float* hp = hid2 + (long)t * kH + c;
  float* op = out + (long)t * kH + c;
#pragma unroll
  for (int j = 0; j < 8; j++) {
    const float m = g0 * (float)o0[c + j] + g1 * (float)o1[c + j];
    op[j] = hp[j] + ls[c + j] * m;
  }
}

// ============================================================================
extern "C" void kernel_launch(void* const* d_in, const int* in_sizes, int n_in,
                              void* d_out, int out_size, void* d_ws, size_t ws_size,
                              hipStream_t stream)
{
  (void)in_sizes; (void)n_in;
  const float* hidden   = (const float*)d_in[0];
  const float* ln1s     = (const float*)d_in[2];
  const float* ln1b     = (const float*)d_in[3];
  const float* ln2s     = (const float*)d_in[4];
  const float* ln2b     = (const float*)d_in[5];
  const float* Wq       = (const float*)d_in[6];
  const float* Wk       = (const float*)d_in[7];
  const float* Wv       = (const float*)d_in[8];
  const float* Wo       = (const float*)d_in[9];
  const float* Wg       = (const float*)d_in[10];
  const float* bg       = (const float*)d_in[11];
  const float* ls_attn  = (const float*)d_in[12];
  const float* ls_moe   = (const float*)d_in[13];
  const float* router_w = (const float*)d_in[14];
  const float* W1       = (const float*)d_in[15];
  const float* b1       = (const float*)d_in[16];
  const float* W2       = (const float*)d_in[17];
  const float* b2       = (const float*)d_in[18];

  char* ws = (char*)d_ws;
  size_t off = 0;
  auto take = [&](size_t b) { size_t r = off; off += (b + 255) & ~(size_t)255; return r; };
  const size_t o_wT   = take(5ULL * kH * kH * 2);              // WqT..WgT,WoT f16
  const size_t o_w1t  = take((size_t)kE * kF * kH * 2);        // W1^T f16
  const size_t o_w2t  = take((size_t)kE * kH * kF * 2);        // W2^T f16
  const size_t o_xn   = take((size_t)kT * kH * 2);             // LN1 out f16
  const size_t o_qkvg = take(4ULL * kT * kH * 4);              // q,k,v,glin fp32
  const size_t o_tab  = take(2ULL * kS * 64 * 4);              // rope cos/sin
  const size_t o_qr   = take(3ULL * kT * kH * 2);              // qr, kr, vt f16
  const size_t o_ctx  = take((size_t)kT * kH * 2);             // attn out f16
  const size_t o_h2   = take((size_t)kT * kH * 4);             // residual fp32
  const size_t o_sm   = take(1 << 20);                         // routing small
  const size_t o_hmid = take((size_t)kE * kCAP * kF * 2);      // expert mid f16
  if (off > ws_size) { hipMemsetAsync(d_out, 0xFF, (size_t)out_size * 4, stream); return; }

  f16* wT    = (f16*)(ws + o_wT);
  f16* w1t   = (f16*)(ws + o_w1t);
  f16* w2t   = (f16*)(ws + o_w2t);
  f16* xn    = (f16*)(ws + o_xn);
  float* qf  = (float*)(ws + o_qkvg);
  float* kfp = qf + (size_t)kT * kH;
  float* vfp = kfp + (size_t)kT * kH;
  float* gfp = vfp + (size_t)kT * kH;
  float* tabc = (float*)(ws + o_tab);
  float* tabs = tabc + (size_t)kS * 64;
  f16* qr  = (f16*)(ws + o_qr);
  f16* kr  = qr + (size_t)kT * kH;
  f16* vt  = kr + (size_t)kT * kH;
  f16* ctx = (f16*)(ws + o_ctx);
  float* h2 = (float*)(ws + o_h2);
  int* eidx    = (int*)(ws + o_sm);
  float* gates = (float*)(ws + o_sm + 65536);
  int* slot    = (int*)(ws + o_sm + 131072);
  int* counts  = (int*)(ws + o_sm + 196608);
  f16* hmid = (f16*)(ws + o_hmid);
  // temporal aliases (q,k,v,g fp32 are dead by the time these are written)
  float* attn_lin = qf;                                            // q slot
  float* x2f = vfp;                                                // v slot
  f16* x2h  = (f16*)(ws + o_qkvg + 1ULL * kT * kH * 4 + (size_t)kT * kH * 2); // k slot hi
  f16* obuf = (f16*)(ws + o_qkvg);                                 // q slot + k lo
  f16* buf  = qr;                                                  // qr/kr/vt region

  const long HH = (long)kH * kH;

  // 1. weight transpose + fp16 convert
  transpose_cvt<<<dim3(32, 32, 1), 256, 0, stream>>>(Wq, wT + 0 * HH, kH, kH, 0, 0);
  transpose_cvt<<<dim3(32, 32, 1), 256, 0, stream>>>(Wk, wT + 1 * HH, kH, kH, 0, 0);
  transpose_cvt<<<dim3(32, 32, 1), 256, 0, stream>>>(Wv, wT + 2 * HH, kH, kH, 0, 0);
  transpose_cvt<<<dim3(32, 32, 1), 256, 0, stream>>>(Wg, wT + 3 * HH, kH, kH, 0, 0);
  transpose_cvt<<<dim3(32, 32, 1), 256, 0, stream>>>(Wo, wT + 4 * HH, kH, kH, 0, 0);
  transpose_cvt<<<dim3(kF / 64, kH / 64, kE), 256, 0, stream>>>(
      W1, w1t, kF, kH, (long)kH * kF, (long)kF * kH);
  transpose_cvt<<<dim3(kH / 64, kF / 64, kE), 256, 0, stream>>>(
      W2, w2t, kH, kF, (long)kF * kH, (long)kH * kF);
  // 2. LN1
  ln_kernel<<<kT, 256, 0, stream>>>(hidden, ln1s, ln1b, xn, nullptr);
  // 3. fused QKV+gate GEMMs (z = 0..3 over Wq,Wk,Wv,Wg)
  gemm_kernel<0><<<dim3(kH / 128, kT / 128, 4), 256, 0, stream>>>(
      xn, wT, qf, nullptr, nullptr, kT, kH, kH, 0L, HH, (long)kT * kH, 0L);
  // 4. RoPE
  rope_table_kernel<<<(kS * 64 + 255) / 256, 256, 0, stream>>>(tabc, tabs);
  rope_kernel<<<kT, 256, 0, stream>>>(qf, kfp, tabc, tabs, qr, kr);
  // 5. V transpose to [BH][HD][S]
  for (int b = 0; b < kB; b++)
    transpose_cvt<<<dim3(kHD / 64, kS / 64, kNH), 256, 0, stream>>>(
        vfp + (size_t)b * kS * kH, vt + (size_t)b * kNH * kHD * kS,
        kH, kS, 128L, (long)kHD * kS);
  // 6. attention
  attn_kernel<<<dim3(kS / 64, kNH, kB), 256, 0, stream>>>(qr, kr, vt, ctx);
  // 7. Wo GEMM
  gemm_kernel<0><<<dim3(kH / 128, kT / 128, 1), 256, 0, stream>>>(
      ctx, wT + 4 * HH, attn_lin, nullptr, nullptr, kT, kH, kH, 0L, 0L, 0L, 0L);
  // 8. gated residual
  combine1_kernel<<<(kT * kH / 4) / 256, 256, 0, stream>>>(
      hidden, attn_lin, gfp, bg, ls_attn, h2);
  // 9. LN2 (f16 for experts, fp32 for router)
  ln_kernel<<<kT, 256, 0, stream>>>(h2, ln2s, ln2b, x2h, x2f);
  // 10-12. routing
  router_kernel<<<kT / 4, 256, 0, stream>>>(x2f, router_w, eidx, gates);
  scan_kernel<<<1, 64, 0, stream>>>(eidx, slot, counts);
  scatter_kernel<<<kTK, 256, 0, stream>>>(x2h, slot, buf);
  // 13. expert GEMM1 + gelu
  gemm_kernel<2><<<dim3(kF / 128, kCAP / 128, kE), 256, 0, stream>>>(
      buf, w1t, hmid, b1, counts, kCAP, kF, kH,
      (long)kCAP * kH, (long)kF * kH, (long)kCAP * kF, (long)kF);
  // 14. expert GEMM2 + bias
  gemm_kernel<3><<<dim3(kH / 128, kCAP / 128, kE), 256, 0, stream>>>(
      hmid, w2t, obuf, b2, counts, kCAP, kH, kF,
      (long)kCAP * kF, (long)kH * kF, (long)kCAP * kH, (long)kH);
  // 15. final combine
  combine2_kernel<<<kT, 256, 0, stream>>>(h2, obuf, slot, gates, ls_moe, (float*)d_out);
}